// Round 13
// baseline (489.796 us; speedup 1.0000x reference)
//
#include <hip/hip_runtime.h>
#include <cstdint>
#include <cmath>

#define NTH 256

namespace {

typedef _Float16 half8  __attribute__((ext_vector_type(8)));
typedef _Float16 half4v __attribute__((ext_vector_type(4)));
typedef _Float16 half2v __attribute__((ext_vector_type(2)));
typedef __fp16   fp16x2 __attribute__((ext_vector_type(2)));
typedef __fp16   fp16x4 __attribute__((ext_vector_type(4)));
typedef float    float4v __attribute__((ext_vector_type(4)));

constexpr int IMG_W   = 100;
constexpr int NS      = 64;
constexpr int D_PTS   = 63;
constexpr int D_DIR   = 27;
constexpr int HID     = 256;
constexpr int HID_DIR = 128;

constexpr int ENC_H = 72;    // enc stride (halfs), 144B rows (16B-aligned -> b128 reads OK)

// hbuf: 64 rows x 256 halfs (512B rows, NO pad) + T2 XOR swizzle (16B granular):
//   idx = row*256 + (col ^ ((row&7)<<3))   [halfs; XOR touches bits 3-5]
// -> b128 reads conflict-spread; 8B writes keep bit 2 -> alignment preserved.
// hd: 64 rows x 128 halfs (256B rows), same swizzle.
// Total scr = 32768 B exactly -> 5 blocks/CU (160KB LDS).
__device__ __forceinline__ int hidx(int row, int col)  { return row * 256 + (col ^ ((row & 7) << 3)); }
__device__ __forceinline__ int hdidx(int row, int col) { return row * 128 + (col ^ ((row & 7) << 3)); }

// Packed fragments [ks][tile][lane][8] (identical lane data for A- or B-side).
// w1 region uses the PERMUTED K order (see kmap1): k'=0..2 -> xyz, k'=3 -> zero pad,
// k' = 4 + 20c + 2l (+1 for cos) -> sin/cos of component c at freq l.
constexpr int W1P_OFF  = 0;
constexpr int W2P_OFF  = 16384;
constexpr int WDP_OFF  = 81920;     // 9 ks x (8 dir tiles + 1 sigma tile) x 512 = 41472
constexpr int WRGB_OFF = 123392;
constexpr int WPACK_HALFS = 125440;    // 250880 bytes

// permuted-k -> original w1 row (k'==3 is the zero pad)
__device__ __forceinline__ int kmap1(int kp) {
    if (kp < 3) return kp;
    const int c = (kp - 4) / 20, rem = (kp - 4) % 20;
    return 3 + 6 * (rem >> 1) + 3 * (rem & 1) + c;
}

__global__ __launch_bounds__(NTH)
void prepack(const float* __restrict__ w1, const float* __restrict__ w2,
             const float* __restrict__ wd, const float* __restrict__ wsig,
             const float* __restrict__ wrgb, _Float16* __restrict__ wp)
{
    const int idx = blockIdx.x * NTH + threadIdx.x;
    if (idx >= WPACK_HALFS) return;
    const int j    = idx & 7;
    const int lane = (idx >> 3) & 63;
    const int kloc = (lane >> 4) * 8 + j;
    const int lr   = lane & 15;
    float v = 0.0f;
    if (idx < W2P_OFF) {                               // w1 (permuted K, pad at k'=3)
        const int nt = (idx >> 9) & 15, ks = idx >> 13;
        const int kp = ks * 32 + kloc;
        if (kp != 3) v = w1[kmap1(kp) * HID + nt * 16 + lr];
    } else if (idx < WDP_OFF) {                        // w2
        const int t = idx - W2P_OFF;
        const int nt = (t >> 9) & 15, ks = t >> 13;
        v = w2[(ks * 32 + kloc) * HID + nt * 16 + lr];
    } else if (idx < WRGB_OFF) {                       // w_dir (K=256 + 27 tail, 9 ks) + sigma col
        const int t = idx - WDP_OFF;
        const int q = t >> 9;                          // 0..80
        const int ks = q / 9, tile = q - 9 * ks;       // ks 0..8
        const int k = ks * 32 + kloc;
        if (tile < 8) { if (k < HID + D_DIR) v = wd[k * HID_DIR + tile * 16 + lr]; }
        else if (lr == 0 && k < HID) v = wsig[k];
    } else {                                           // w_rgb (N=3 in 16-tile)
        const int t = idx - WRGB_OFF;
        const int ks = t >> 9;
        const int k = ks * 32 + kloc;
        if (lr < 3) v = wrgb[k * 3 + lr];
    }
    wp[idx] = (_Float16)v;
}

// Fallback gathers (no workspace).
__device__ __forceinline__ half8 bf_w1p(const float* __restrict__ W, int kbase, int n) {
    half8 b;
    #pragma unroll
    for (int j = 0; j < 8; ++j) {
        const int kp = kbase + j;
        b[j] = (_Float16)((kp != 3) ? W[kmap1(kp) * HID + n] : 0.0f);
    }
    return b;
}
__device__ __forceinline__ half8 bf_w(const float* __restrict__ W, int ldN,
                                      int kbase, int n, int kmax) {
    half8 b;
    #pragma unroll
    for (int j = 0; j < 8; ++j) {
        const int k = kbase + j;
        b[j] = (_Float16)((k < kmax) ? W[k * ldN + n] : 0.0f);
    }
    return b;
}
__device__ __forceinline__ half8 bf_sig(const float* __restrict__ ws, int kbase, int lr) {
    half8 b;
    #pragma unroll
    for (int j = 0; j < 8; ++j)
        b[j] = (_Float16)((lr == 0) ? ws[kbase + j] : 0.0f);
    return b;
}
__device__ __forceinline__ half8 bf_rgb(const float* __restrict__ wr, int kbase, int lr) {
    half8 b;
    #pragma unroll
    for (int j = 0; j < 8; ++j)
        b[j] = (_Float16)((lr < 3) ? wr[(kbase + j) * 3 + lr] : 0.0f);
    return b;
}

// relu + f32->f16: cvt_pkrtz pair-convert, then packed f16 max (v_pk_max_f16 via
// __builtin_elementwise_max on an fp16 vector). rtz(relu(x)) == relu(rtz(x)) bitwise.
__device__ __forceinline__ half4v pack_relu4(const float4v a) {
    const fp16x2 lo = __builtin_amdgcn_cvt_pkrtz(a[0], a[1]);
    const fp16x2 hi = __builtin_amdgcn_cvt_pkrtz(a[2], a[3]);
    fp16x4 r4 = __builtin_shufflevector(lo, hi, 0, 1, 2, 3);
    r4 = __builtin_elementwise_max(r4, fp16x4{});
    return __builtin_bit_cast(half4v, r4);
}

// hw sin/cos of x radians (v_sin/v_cos take revolutions; floor-based range reduce).
constexpr float INV2PI = 0.15915494309189535f;
__device__ __forceinline__ float hsin_rev(float f) {
    const float fr = f - floorf(f);
    return __builtin_amdgcn_sinf(fr);
}
__device__ __forceinline__ float hcos_rev(float f) {
    const float fr = f - floorf(f);
    return __builtin_amdgcn_cosf(fr);
}

// np.linspace-style stratified z (exact f64 chain, t[63]=1 exact).
__device__ __forceinline__ double z_of(int s, const float* __restrict__ t_rand) {
    const double delta = 1.0 / 63.0;
    const double ts = (s == 63) ? 1.0 : (double)s * delta;
    const double zs = 2.0 * (1.0 - ts) + 6.0 * ts;
    double lower, upper;
    if (s == 0) { lower = zs; }
    else { const double tm = (double)(s - 1) * delta;
           const double zm = 2.0 * (1.0 - tm) + 6.0 * tm; lower = 0.5 * (zm + zs); }
    if (s == 63) { upper = zs; }
    else { const double tp = (s + 1 == 63) ? 1.0 : (double)(s + 1) * delta;
           const double zp = 2.0 * (1.0 - tp) + 6.0 * tp; upper = 0.5 * (zs + zp); }
    return lower + (upper - lower) * (double)t_rand[s];
}

template<bool PACKED>
__global__ __launch_bounds__(NTH, 5)
void nerf_fused(const float* __restrict__ c2w,
                const float* __restrict__ t_rand,
                const float* __restrict__ w1,  const float* __restrict__ b1,
                const float* __restrict__ w2,  const float* __restrict__ b2,
                const float* __restrict__ w_sig, const float* __restrict__ b_sig,
                const float* __restrict__ w_dir, const float* __restrict__ b_dir,
                const float* __restrict__ w_rgb, const float* __restrict__ b_rgb,
                const _Float16* __restrict__ wpack,
                float* __restrict__ out)
{
    // Single 32KB arena, time-multiplexed (barrier-separated):
    //   enc  : encH 64x72 halfs (9216 B, rows 144B, unswizzled)
    //   H    : hbuf 64x256 halfs swizzled (32768 B)       [H1 -> H2]
    //   HD   : hd 64x128 halfs swizzled (16384 B)         [dir out]
    //   tail : sigp @20480 (1KB), sigb @21504 (256B), rgbb @21760 (768B)
    //          (all > HD's 16KB; written only after H2 dead)
    //   razor: f64 buffers @0..4608 (after rgb)
    __shared__ __align__(16) unsigned char scr[32768];
    _Float16* encH = reinterpret_cast<_Float16*>(scr);
    _Float16* hbuf = reinterpret_cast<_Float16*>(scr);
    _Float16* hdb  = reinterpret_cast<_Float16*>(scr);
    double*   encD = reinterpret_cast<double*>(scr);                   //  512 B
    double*   h1d  = reinterpret_cast<double*>(scr + 512);             // 2048 B
    double*   h2d  = reinterpret_cast<double*>(scr + 2560);            // 2048 B
    float*    sigp = reinterpret_cast<float*>(scr + 20480);            // [4][64]
    float*    sigb = reinterpret_cast<float*>(scr + 21504);            // [64]
    float*    rgbb = reinterpret_cast<float*>(scr + 21760);            // [64*3]

    const int tid  = threadIdx.x;
    const int ray  = blockIdx.x;
    const int lane = tid & 63;
    const int wv   = tid >> 6;
    const int lr   = lane & 15;
    const int lq   = lane >> 4;

    const half8* wp8 = reinterpret_cast<const half8*>(wpack);

    // ---- per-ray setup ----
    const int pj = ray / IMG_W;
    const int pi = ray - pj * IMG_W;
    const float dx = ((float)pi - 50.0f) / 86.6f;
    const float dy = -(((float)pj) - 50.0f) / 86.6f;
    const float rd0 = dx * c2w[0] + dy * c2w[1] - c2w[2];
    const float rd1 = dx * c2w[4] + dy * c2w[5] - c2w[6];
    const float rd2 = dx * c2w[8] + dy * c2w[9] - c2w[10];
    const float ro0 = c2w[3], ro1 = c2w[7], ro2 = c2w[11];
    const float nrm = sqrtf(rd0 * rd0 + rd1 * rd1 + rd2 * rd2);
    const float vd0 = rd0 / nrm, vd1 = rd1 / nrm, vd2 = rd2 / nrm;

    // ---- enc_dir fragment in registers (27 lanes compute 1 dim, 8 shfl gather) ----
    half8 he;
    {
        float edv = 0.0f;
        if (lane < D_DIR) {
            const int f = lane;
            if (f < 3) {
                edv = (f == 0) ? vd0 : ((f == 1) ? vd1 : vd2);
            } else {
                const int ff = f - 3;
                const int l = ff / 6;
                const int r = ff - 6 * l;
                const int c = r % 3;
                const float x = ((c == 0) ? vd0 : ((c == 1) ? vd1 : vd2)) * (float)(1 << l);
                edv = (r < 3) ? hsin_rev(x * INV2PI) : hcos_rev(x * INV2PI);
            }
        }
        #pragma unroll
        for (int j = 0; j < 8; ++j)
            he[j] = (_Float16)__shfl(edv, lq * 8 + j, 64);   // lanes >= 27 hold 0
    }

    // ---- L1 weight/bias prefetch: issue before the enc phase; L2 latency hides under trig ----
    half8 w1pf[2][4];
    float4v b1pf[4];
    if (PACKED) {
        #pragma unroll
        for (int ks = 0; ks < 2; ++ks)
            #pragma unroll
            for (int nt = 0; nt < 4; ++nt)
                w1pf[ks][nt] = wp8[(W1P_OFF >> 3) + (ks * 16 + wv * 4 + nt) * 64 + lane];
    }
    #pragma unroll
    for (int nt = 0; nt < 4; ++nt)
        b1pf[nt] = *reinterpret_cast<const float4v*>(&b1[(wv * 4 + nt) * 16 + lq * 4]);

    // ---- phase E: enc_pts (waves 0-2, inline z, hw sin/cos, permuted K layout) ----
    // col 0..2 = xyz, col 3 = pad(0), cols 4+20c+2l = {sin,cos} packed b32 per thread.
    if (tid < 192) {
        const int s = tid / 3;
        const int c = tid - 3 * s;
        const float zv = (float)z_of(s, t_rand);
        const float p = (c == 0) ? (ro0 + rd0 * zv) : ((c == 1) ? (ro1 + rd1 * zv) : (ro2 + rd2 * zv));
        _Float16* row = &encH[s * ENC_H];
        if (c == 2) {
            *reinterpret_cast<half2v*>(&row[2]) = half2v{(_Float16)p, (_Float16)0.0f};
        } else {
            row[c] = (_Float16)p;
        }
        unsigned* rowu = reinterpret_cast<unsigned*>(row);
        #pragma unroll
        for (int l = 0; l < 10; ++l) {
            const float f = p * ((float)(1 << l) * INV2PI);
            const float fr = f - floorf(f);
            const fp16x2 sc = __builtin_amdgcn_cvt_pkrtz(__builtin_amdgcn_sinf(fr),
                                                         __builtin_amdgcn_cosf(fr));
            rowu[2 + 10 * c + l] = __builtin_bit_cast(unsigned, sc);
        }
    }
    __syncthreads();

    // ======== layer 1 (MFMA, swapped operands): C'[neuron][sample] ========
    half8 w2pf[4];   // L2 ks=0 prefetch (loaded below, before the barrier)
    {
        float4v acc[4][4];   // [nt][st]
        #pragma unroll
        for (int nt = 0; nt < 4; ++nt)
            #pragma unroll
            for (int st = 0; st < 4; ++st) acc[nt][st] = b1pf[nt];

        #pragma unroll
        for (int ks = 0; ks < 2; ++ks) {
            half8 h[4];
            #pragma unroll
            for (int st = 0; st < 4; ++st)
                h[st] = *reinterpret_cast<const half8*>(&encH[(st * 16 + lr) * ENC_H + ks * 32 + lq * 8]);
            __builtin_amdgcn_s_setprio(1);
            #pragma unroll
            for (int nt = 0; nt < 4; ++nt) {
                const half8 w = PACKED
                    ? w1pf[ks][nt]
                    : bf_w1p(w1, ks * 32 + lq * 8, (wv * 4 + nt) * 16 + lr);
                #pragma unroll
                for (int st = 0; st < 4; ++st)
                    acc[nt][st] = __builtin_amdgcn_mfma_f32_16x16x32_f16(w, h[st], acc[nt][st], 0, 0, 0);
            }
            __builtin_amdgcn_s_setprio(0);
        }
        if (PACKED) {   // prefetch L2 ks=0 weights across the barrier
            #pragma unroll
            for (int nt = 0; nt < 4; ++nt)
                w2pf[nt] = wp8[(W2P_OFF >> 3) + (wv * 4 + nt) * 64 + lane];
        }
        __syncthreads();   // ALL encH reads complete (hbuf aliases encH)
        #pragma unroll
        for (int nt = 0; nt < 4; ++nt) {
            const int nb = (wv * 4 + nt) * 16 + lq * 4;
            #pragma unroll
            for (int st = 0; st < 4; ++st)
                *reinterpret_cast<half4v*>(&hbuf[hidx(st * 16 + lr, nb)]) = pack_relu4(acc[nt][st]);
        }
    }
    __syncthreads();

    // ======== layer 2 (MFMA): H2 = relu(H1 @ w2 + b2) ========
    half8 wdpf[2];   // dir ks=0 prefetch (loaded below, before the barrier)
    {
        float4v acc[4][4];
        #pragma unroll
        for (int nt = 0; nt < 4; ++nt) {
            const float4v bb = *reinterpret_cast<const float4v*>(&b2[(wv * 4 + nt) * 16 + lq * 4]);
            #pragma unroll
            for (int st = 0; st < 4; ++st) acc[nt][st] = bb;
        }

        // ks = 0 (prefetched weights)
        {
            half8 h[4];
            #pragma unroll
            for (int st = 0; st < 4; ++st)
                h[st] = *reinterpret_cast<const half8*>(&hbuf[hidx(st * 16 + lr, lq * 8)]);
            __builtin_amdgcn_s_setprio(1);
            #pragma unroll
            for (int nt = 0; nt < 4; ++nt) {
                const half8 w = PACKED
                    ? w2pf[nt]
                    : bf_w(w2, HID, lq * 8, (wv * 4 + nt) * 16 + lr, 1 << 30);
                #pragma unroll
                for (int st = 0; st < 4; ++st)
                    acc[nt][st] = __builtin_amdgcn_mfma_f32_16x16x32_f16(w, h[st], acc[nt][st], 0, 0, 0);
            }
            __builtin_amdgcn_s_setprio(0);
        }
        #pragma unroll
        for (int ks = 1; ks < 8; ++ks) {
            half8 h[4];
            #pragma unroll
            for (int st = 0; st < 4; ++st)
                h[st] = *reinterpret_cast<const half8*>(&hbuf[hidx(st * 16 + lr, ks * 32 + lq * 8)]);
            const half8* wk = wp8 + (W2P_OFF >> 3) + (ks * 16 + wv * 4) * 64 + lane;
            __builtin_amdgcn_s_setprio(1);
            #pragma unroll
            for (int nt = 0; nt < 4; ++nt) {
                const half8 w = PACKED
                    ? wk[nt * 64]
                    : bf_w(w2, HID, ks * 32 + lq * 8, (wv * 4 + nt) * 16 + lr, 1 << 30);
                #pragma unroll
                for (int st = 0; st < 4; ++st)
                    acc[nt][st] = __builtin_amdgcn_mfma_f32_16x16x32_f16(w, h[st], acc[nt][st], 0, 0, 0);
            }
            __builtin_amdgcn_s_setprio(0);
        }
        if (PACKED) {   // prefetch dir ks=0 weights across the barrier
            #pragma unroll
            for (int nt = 0; nt < 2; ++nt)
                wdpf[nt] = wp8[(WDP_OFF >> 3) + (wv * 2 + nt) * 64 + lane];
        }
        __syncthreads();   // all H1 reads complete before in-place overwrite
        #pragma unroll
        for (int nt = 0; nt < 4; ++nt) {
            const int nb = (wv * 4 + nt) * 16 + lq * 4;
            #pragma unroll
            for (int st = 0; st < 4; ++st)
                *reinterpret_cast<half4v*>(&hbuf[hidx(st * 16 + lr, nb)]) = pack_relu4(acc[nt][st]);
        }
    }
    __syncthreads();

    // ======== dir layer + sigma (MFMA, K=256 + 27-dim enc_dir tail as 9th ks) ========
    // Sigma balanced: wave w accumulates sigma over ks in {2w, 2w+1}; partials summed later.
    float4v accd[2][4];
    float4v accs[4];
    {
        #pragma unroll
        for (int nt = 0; nt < 2; ++nt) {
            const float4v bb = *reinterpret_cast<const float4v*>(&b_dir[(wv * 2 + nt) * 16 + lq * 4]);
            #pragma unroll
            for (int st = 0; st < 4; ++st) accd[nt][st] = bb;
        }
        #pragma unroll
        for (int st = 0; st < 4; ++st) accs[st] = float4v{0.f, 0.f, 0.f, 0.f};

        // ks = 0 (prefetched dir weights; sigma ks0 belongs to wave 0)
        {
            half8 h[4];
            #pragma unroll
            for (int st = 0; st < 4; ++st)
                h[st] = *reinterpret_cast<const half8*>(&hbuf[hidx(st * 16 + lr, lq * 8)]);
            __builtin_amdgcn_s_setprio(1);
            #pragma unroll
            for (int nt = 0; nt < 2; ++nt) {
                const half8 w = PACKED
                    ? wdpf[nt]
                    : bf_w(w_dir, HID_DIR, lq * 8, (wv * 2 + nt) * 16 + lr, 1 << 30);
                #pragma unroll
                for (int st = 0; st < 4; ++st)
                    accd[nt][st] = __builtin_amdgcn_mfma_f32_16x16x32_f16(w, h[st], accd[nt][st], 0, 0, 0);
            }
            if (wv == 0) {
                const half8 w = PACKED
                    ? wp8[(WDP_OFF >> 3) + 8 * 64 + lane]
                    : bf_sig(w_sig, lq * 8, lr);
                #pragma unroll
                for (int st = 0; st < 4; ++st)
                    accs[st] = __builtin_amdgcn_mfma_f32_16x16x32_f16(w, h[st], accs[st], 0, 0, 0);
            }
            __builtin_amdgcn_s_setprio(0);
        }
        #pragma unroll
        for (int ks = 1; ks < 8; ++ks) {
            half8 h[4];
            #pragma unroll
            for (int st = 0; st < 4; ++st)
                h[st] = *reinterpret_cast<const half8*>(&hbuf[hidx(st * 16 + lr, ks * 32 + lq * 8)]);
            const half8* wk = wp8 + (WDP_OFF >> 3) + (ks * 9 + wv * 2) * 64 + lane;
            __builtin_amdgcn_s_setprio(1);
            #pragma unroll
            for (int nt = 0; nt < 2; ++nt) {
                const half8 w = PACKED
                    ? wk[nt * 64]
                    : bf_w(w_dir, HID_DIR, ks * 32 + lq * 8, (wv * 2 + nt) * 16 + lr, 1 << 30);
                #pragma unroll
                for (int st = 0; st < 4; ++st)
                    accd[nt][st] = __builtin_amdgcn_mfma_f32_16x16x32_f16(w, h[st], accd[nt][st], 0, 0, 0);
            }
            if ((ks >> 1) == wv) {   // this wave's sigma K-slice
                const half8 w = PACKED
                    ? wp8[(WDP_OFF >> 3) + (ks * 9 + 8) * 64 + lane]
                    : bf_sig(w_sig, ks * 32 + lq * 8, lr);
                #pragma unroll
                for (int st = 0; st < 4; ++st)
                    accs[st] = __builtin_amdgcn_mfma_f32_16x16x32_f16(w, h[st], accs[st], 0, 0, 0);
            }
            __builtin_amdgcn_s_setprio(0);
        }
        // tail ks=8: B = enc_dir (ray-uniform, in registers)
        {
            const half8* wk = wp8 + (WDP_OFF >> 3) + (8 * 9 + wv * 2) * 64 + lane;
            __builtin_amdgcn_s_setprio(1);
            #pragma unroll
            for (int nt = 0; nt < 2; ++nt) {
                const half8 w = PACKED
                    ? wk[nt * 64]
                    : bf_w(w_dir, HID_DIR, HID + lq * 8, (wv * 2 + nt) * 16 + lr, HID + D_DIR);
                #pragma unroll
                for (int st = 0; st < 4; ++st)
                    accd[nt][st] = __builtin_amdgcn_mfma_f32_16x16x32_f16(w, he, accd[nt][st], 0, 0, 0);
            }
            __builtin_amdgcn_s_setprio(0);
        }
    }
    __syncthreads();   // all H2 reads complete

    // HD -> hdb (swizzled); sigma partials -> sigp (beyond HD's 16KB)
    #pragma unroll
    for (int nt = 0; nt < 2; ++nt) {
        const int nb = (wv * 2 + nt) * 16 + lq * 4;
        #pragma unroll
        for (int st = 0; st < 4; ++st)
            *reinterpret_cast<half4v*>(&hdb[hdidx(st * 16 + lr, nb)]) = pack_relu4(accd[nt][st]);
    }
    if (lq == 0) {
        #pragma unroll
        for (int st = 0; st < 4; ++st)
            sigp[wv * NS + st * 16 + lr] = accs[st][0];
    }
    __syncthreads();

    // ======== rgb head (MFMA): wave wv handles sample-tile wv ========
    // First 64 threads concurrently reduce the sigma partials (ready before next barrier).
    if (tid < NS)
        sigb[tid] = ((sigp[0 * NS + tid] + sigp[1 * NS + tid]) +
                     (sigp[2 * NS + tid] + sigp[3 * NS + tid])) + b_sig[0];
    {
        float4v accr = float4v{0.f, 0.f, 0.f, 0.f};
        const half8* wk = wp8 + (WRGB_OFF >> 3) + lane;
        __builtin_amdgcn_s_setprio(1);
        #pragma unroll
        for (int ks = 0; ks < 4; ++ks) {
            const half8 h = *reinterpret_cast<const half8*>(&hdb[hdidx(wv * 16 + lr, ks * 32 + lq * 8)]);
            const half8 w = PACKED
                ? wk[ks * 64]
                : bf_rgb(w_rgb, ks * 32 + lq * 8, lr);
            accr = __builtin_amdgcn_mfma_f32_16x16x32_f16(w, h, accr, 0, 0, 0);
        }
        __builtin_amdgcn_s_setprio(0);
        if (lq == 0) {
            #pragma unroll
            for (int r = 0; r < 3; ++r) {
                const float a = accr[r] + b_rgb[r];
                rgbb[(wv * 16 + lr) * 3 + r] = 1.0f / (1.0f + expf(-a));
            }
        }
    }
    __syncthreads();   // rgb reads + sigb reduction done -> scr low region reusable by razor

    // ======== conditional f64 razor for sigma[63] (aliases scr bytes 0..4608) ========
    // Threshold 0.01: main-path sigma error ~3e-4 (<=1e-3 pessimistic) -> 10x margin.
    if (fabsf(sigb[63]) < 0.01f) {
        {
            const double z63 = z_of(63, t_rand);
            const double p0 = (double)ro0 + (double)rd0 * z63;
            const double p1 = (double)ro1 + (double)rd1 * z63;
            const double p2 = (double)ro2 + (double)rd2 * z63;
            if (tid < D_PTS) {
                const int f = tid;
                double v;
                if (f < 3) {
                    v = (f == 0) ? p0 : ((f == 1) ? p1 : p2);
                } else {
                    const int ff = f - 3;
                    const int l = ff / 6;
                    const int r = ff - 6 * l;
                    const int c = r % 3;
                    const double x = ((c == 0) ? p0 : ((c == 1) ? p1 : p2)) * (double)(1 << l);
                    v = (r < 3) ? sin(x) : cos(x);
                }
                encD[f] = v;
            }
        }
        __syncthreads();
        {
            double a0 = 0.0, a1 = 0.0, a2 = 0.0, a3 = 0.0;
            int k = 0;
            for (; k + 4 <= 60; k += 4) {
                a0 += encD[k]     * (double)w1[(k)     * HID + tid];
                a1 += encD[k + 1] * (double)w1[(k + 1) * HID + tid];
                a2 += encD[k + 2] * (double)w1[(k + 2) * HID + tid];
                a3 += encD[k + 3] * (double)w1[(k + 3) * HID + tid];
            }
            a0 += encD[60] * (double)w1[60 * HID + tid];
            a1 += encD[61] * (double)w1[61 * HID + tid];
            a2 += encD[62] * (double)w1[62 * HID + tid];
            const double acc = ((a0 + a1) + (a2 + a3)) + (double)b1[tid];
            h1d[tid] = fmax(acc, 0.0);
        }
        __syncthreads();
        {
            double a0 = 0.0, a1 = 0.0, a2 = 0.0, a3 = 0.0;
            for (int k = 0; k < HID; k += 4) {
                a0 += h1d[k]     * (double)w2[(k)     * HID + tid];
                a1 += h1d[k + 1] * (double)w2[(k + 1) * HID + tid];
                a2 += h1d[k + 2] * (double)w2[(k + 2) * HID + tid];
                a3 += h1d[k + 3] * (double)w2[(k + 3) * HID + tid];
            }
            const double acc = ((a0 + a1) + (a2 + a3)) + (double)b2[tid];
            h2d[tid] = fmax(acc, 0.0);
        }
        __syncthreads();
        if (tid < 64) {
            double p = 0.0;
            #pragma unroll
            for (int m = 0; m < 4; ++m)
                p += h2d[tid * 4 + m] * (double)w_sig[tid * 4 + m];
            #pragma unroll
            for (int off = 1; off < 64; off <<= 1)
                p += __shfl_xor(p, off, 64);
            if (tid == 0) sigb[63] = (float)(p + (double)b_sig[0]);
        }
    }
    __syncthreads();

    // ======== volume compositing (wave 0, inline z) ========
    if (tid < NS) {
        const int s = tid;
        const float sgv = sigb[s];
        const float zv  = (float)z_of(s, t_rand);
        const float zn  = __shfl_down(zv, 1, 64);
        const float dist = (s < 63) ? (zn - zv) : 1.0e10f;
        const float alpha = 1.0f - expf(-fmaxf(sgv, 0.0f) * dist * nrm);
        float P = 1.0f - alpha;
        #pragma unroll
        for (int off = 1; off < 64; off <<= 1) {
            const float p = __shfl_up(P, off, 64);
            if (s >= off) P *= p;
        }
        float T = __shfl_up(P, 1, 64);
        if (s == 0) T = 1.0f;
        const float wgt = alpha * T;
        float r0 = wgt * rgbb[s * 3 + 0];
        float r1 = wgt * rgbb[s * 3 + 1];
        float r2 = wgt * rgbb[s * 3 + 2];
        #pragma unroll
        for (int off = 32; off > 0; off >>= 1) {
            r0 += __shfl_xor(r0, off, 64);
            r1 += __shfl_xor(r1, off, 64);
            r2 += __shfl_xor(r2, off, 64);
        }
        if (s == 0) {
            out[ray * 3 + 0] = r0;
            out[ray * 3 + 1] = r1;
            out[ray * 3 + 2] = r2;
        }
    }
}

} // namespace

extern "C" void kernel_launch(void* const* d_in, const int* in_sizes, int n_in,
                              void* d_out, int out_size, void* d_ws, size_t ws_size,
                              hipStream_t stream) {
    const float* c2w    = (const float*)d_in[0];
    const float* t_rand = (const float*)d_in[1];
    const float* w1     = (const float*)d_in[2];
    const float* b1     = (const float*)d_in[3];
    const float* w2     = (const float*)d_in[4];
    const float* b2     = (const float*)d_in[5];
    const float* w_sig  = (const float*)d_in[6];
    const float* b_sig  = (const float*)d_in[7];
    const float* w_dir  = (const float*)d_in[8];
    const float* b_dir  = (const float*)d_in[9];
    const float* w_rgb  = (const float*)d_in[10];
    const float* b_rgb  = (const float*)d_in[11];

    (void)in_sizes; (void)n_in; (void)out_size;

    const bool packed = (ws_size >= (size_t)(WPACK_HALFS * 2));
    if (packed) {
        _Float16* wp = (_Float16*)d_ws;
        hipLaunchKernelGGL(prepack, dim3((WPACK_HALFS + NTH - 1) / NTH), dim3(NTH), 0, stream,
                           w1, w2, w_dir, w_sig, w_rgb, wp);
        hipLaunchKernelGGL((nerf_fused<true>), dim3(100 * 100), dim3(NTH), 0, stream,
                           c2w, t_rand, w1, b1, w2, b2, w_sig, b_sig,
                           w_dir, b_dir, w_rgb, b_rgb, (const _Float16*)wp, (float*)d_out);
    } else {
        hipLaunchKernelGGL((nerf_fused<false>), dim3(100 * 100), dim3(NTH), 0, stream,
                           c2w, t_rand, w1, b1, w2, b2, w_sig, b_sig,
                           w_dir, b_dir, w_rgb, b_rgb, (const _Float16*)nullptr, (float*)d_out);
    }
}

// Round 14
// 246.722 us; speedup vs baseline: 1.9852x; 1.9852x over previous
//
#include <hip/hip_runtime.h>
#include <cstdint>
#include <cmath>

#define NTH 256

namespace {

typedef _Float16 half8  __attribute__((ext_vector_type(8)));
typedef _Float16 half4v __attribute__((ext_vector_type(4)));
typedef _Float16 half2v __attribute__((ext_vector_type(2)));
typedef __fp16   fp16x2 __attribute__((ext_vector_type(2)));
typedef __fp16   fp16x4 __attribute__((ext_vector_type(4)));
typedef float    float4v __attribute__((ext_vector_type(4)));

constexpr int IMG_W   = 100;
constexpr int NS      = 64;
constexpr int D_PTS   = 63;
constexpr int D_DIR   = 27;
constexpr int HID     = 256;
constexpr int HID_DIR = 128;

constexpr int ENC_H = 72;    // enc stride (halfs), 144B rows (16B-aligned -> b128 reads OK)
constexpr int H_S   = 260;   // hbuf stride (halfs): 520B rows = 65 (odd) 8B-units mod 16
constexpr int HD_S  = 132;   // hd stride (halfs): 264B rows = 33 (odd) 8B-units

// Packed fragments [ks][tile][lane][8] (identical lane data for A- or B-side).
// w1 region uses the PERMUTED K order (see kmap1): k'=0..2 -> xyz, k'=3 -> zero pad,
// k' = 4 + 20c + 2l (+1 for cos) -> sin/cos of component c at freq l. Dot products are
// K-order invariant; enc fill writes the same order, so MFMA semantics are unchanged.
constexpr int W1P_OFF  = 0;
constexpr int W2P_OFF  = 16384;
constexpr int WDP_OFF  = 81920;     // 9 ks x (8 dir tiles + 1 sigma tile) x 512 = 41472
constexpr int WRGB_OFF = 123392;
constexpr int WPACK_HALFS = 125440;    // 250880 bytes

// permuted-k -> original w1 row (k'==3 is the zero pad)
__device__ __forceinline__ int kmap1(int kp) {
    if (kp < 3) return kp;
    const int c = (kp - 4) / 20, rem = (kp - 4) % 20;
    return 3 + 6 * (rem >> 1) + 3 * (rem & 1) + c;
}

__global__ __launch_bounds__(NTH)
void prepack(const float* __restrict__ w1, const float* __restrict__ w2,
             const float* __restrict__ wd, const float* __restrict__ wsig,
             const float* __restrict__ wrgb, _Float16* __restrict__ wp)
{
    const int idx = blockIdx.x * NTH + threadIdx.x;
    if (idx >= WPACK_HALFS) return;
    const int j    = idx & 7;
    const int lane = (idx >> 3) & 63;
    const int kloc = (lane >> 4) * 8 + j;
    const int lr   = lane & 15;
    float v = 0.0f;
    if (idx < W2P_OFF) {                               // w1 (permuted K, pad at k'=3)
        const int nt = (idx >> 9) & 15, ks = idx >> 13;
        const int kp = ks * 32 + kloc;
        if (kp != 3) v = w1[kmap1(kp) * HID + nt * 16 + lr];
    } else if (idx < WDP_OFF) {                        // w2
        const int t = idx - W2P_OFF;
        const int nt = (t >> 9) & 15, ks = t >> 13;
        v = w2[(ks * 32 + kloc) * HID + nt * 16 + lr];
    } else if (idx < WRGB_OFF) {                       // w_dir (K=256 + 27 tail, 9 ks) + sigma col
        const int t = idx - WDP_OFF;
        const int q = t >> 9;                          // 0..80
        const int ks = q / 9, tile = q - 9 * ks;       // ks 0..8
        const int k = ks * 32 + kloc;
        if (tile < 8) { if (k < HID + D_DIR) v = wd[k * HID_DIR + tile * 16 + lr]; }
        else if (lr == 0 && k < HID) v = wsig[k];
    } else {                                           // w_rgb (N=3 in 16-tile)
        const int t = idx - WRGB_OFF;
        const int ks = t >> 9;
        const int k = ks * 32 + kloc;
        if (lr < 3) v = wrgb[k * 3 + lr];
    }
    wp[idx] = (_Float16)v;
}

// Fallback gathers (no workspace).
__device__ __forceinline__ half8 bf_w1p(const float* __restrict__ W, int kbase, int n) {
    half8 b;
    #pragma unroll
    for (int j = 0; j < 8; ++j) {
        const int kp = kbase + j;
        b[j] = (_Float16)((kp != 3) ? W[kmap1(kp) * HID + n] : 0.0f);
    }
    return b;
}
__device__ __forceinline__ half8 bf_w(const float* __restrict__ W, int ldN,
                                      int kbase, int n, int kmax) {
    half8 b;
    #pragma unroll
    for (int j = 0; j < 8; ++j) {
        const int k = kbase + j;
        b[j] = (_Float16)((k < kmax) ? W[k * ldN + n] : 0.0f);
    }
    return b;
}
__device__ __forceinline__ half8 bf_sig(const float* __restrict__ ws, int kbase, int lr) {
    half8 b;
    #pragma unroll
    for (int j = 0; j < 8; ++j)
        b[j] = (_Float16)((lr == 0) ? ws[kbase + j] : 0.0f);
    return b;
}
__device__ __forceinline__ half8 bf_rgb(const float* __restrict__ wr, int kbase, int lr) {
    half8 b;
    #pragma unroll
    for (int j = 0; j < 8; ++j)
        b[j] = (_Float16)((lr < 3) ? wr[(kbase + j) * 3 + lr] : 0.0f);
    return b;
}

// 16B fragment from an 8B-aligned LDS row (H_S/HD_S are odd multiples of 8B).
__device__ __forceinline__ half8 ld_h8(const _Float16* __restrict__ p) {
    const half4v lo = *reinterpret_cast<const half4v*>(p);
    const half4v hi = *reinterpret_cast<const half4v*>(p + 4);
    return __builtin_shufflevector(lo, hi, 0, 1, 2, 3, 4, 5, 6, 7);
}

// relu + f32->f16: cvt_pkrtz pair-convert, then packed f16 max (v_pk_max_f16 via
// __builtin_elementwise_max on an fp16 vector). rtz(relu(x)) == relu(rtz(x)) bitwise.
__device__ __forceinline__ half4v pack_relu4(const float4v a) {
    const fp16x2 lo = __builtin_amdgcn_cvt_pkrtz(a[0], a[1]);
    const fp16x2 hi = __builtin_amdgcn_cvt_pkrtz(a[2], a[3]);
    fp16x4 r4 = __builtin_shufflevector(lo, hi, 0, 1, 2, 3);
    r4 = __builtin_elementwise_max(r4, fp16x4{});
    return __builtin_bit_cast(half4v, r4);
}

// hw sin/cos of x radians (v_sin/v_cos take revolutions; floor-based range reduce).
constexpr float INV2PI = 0.15915494309189535f;
__device__ __forceinline__ float hsin_rev(float f) {
    const float fr = f - floorf(f);
    return __builtin_amdgcn_sinf(fr);
}
__device__ __forceinline__ float hcos_rev(float f) {
    const float fr = f - floorf(f);
    return __builtin_amdgcn_cosf(fr);
}

// np.linspace-style stratified z (exact f64 chain, t[63]=1 exact).
__device__ __forceinline__ double z_of(int s, const float* __restrict__ t_rand) {
    const double delta = 1.0 / 63.0;
    const double ts = (s == 63) ? 1.0 : (double)s * delta;
    const double zs = 2.0 * (1.0 - ts) + 6.0 * ts;
    double lower, upper;
    if (s == 0) { lower = zs; }
    else { const double tm = (double)(s - 1) * delta;
           const double zm = 2.0 * (1.0 - tm) + 6.0 * tm; lower = 0.5 * (zm + zs); }
    if (s == 63) { upper = zs; }
    else { const double tp = (s + 1 == 63) ? 1.0 : (double)(s + 1) * delta;
           const double zp = 2.0 * (1.0 - tp) + 6.0 * tp; upper = 0.5 * (zs + zp); }
    return lower + (upper - lower) * (double)t_rand[s];
}

template<bool PACKED>
__global__ __launch_bounds__(NTH, 4)
void nerf_fused(const float* __restrict__ c2w,
                const float* __restrict__ t_rand,
                const float* __restrict__ w1,  const float* __restrict__ b1,
                const float* __restrict__ w2,  const float* __restrict__ b2,
                const float* __restrict__ w_sig, const float* __restrict__ b_sig,
                const float* __restrict__ w_dir, const float* __restrict__ b_dir,
                const float* __restrict__ w_rgb, const float* __restrict__ b_rgb,
                const _Float16* __restrict__ wpack,
                float* __restrict__ out)
{
    __shared__ __align__(16) unsigned char scr[NS * H_S * 2];          // 33280 B
    _Float16* encH = reinterpret_cast<_Float16*>(scr);
    _Float16* hbuf = reinterpret_cast<_Float16*>(scr);
    double*   encD = reinterpret_cast<double*>(scr);                   //  512 B
    double*   h1d  = reinterpret_cast<double*>(scr + 512);             // 2048 B
    double*   h2d  = reinterpret_cast<double*>(scr + 2560);            // 2048 B
    __shared__ __align__(16) _Float16 encdirH[32];
    __shared__ float  sigp[4][NS];    // per-wave sigma partials (balanced sigma)
    __shared__ float  sigb[NS];
    __shared__ float  rgbb[NS * 3];

    const int tid  = threadIdx.x;
    const int ray  = blockIdx.x;
    const int lane = tid & 63;
    const int wv   = tid >> 6;
    const int lr   = lane & 15;
    const int lq   = lane >> 4;

    const half8* wp8 = reinterpret_cast<const half8*>(wpack);

    // ---- per-ray setup ----
    const int pj = ray / IMG_W;
    const int pi = ray - pj * IMG_W;
    const float dx = ((float)pi - 50.0f) / 86.6f;
    const float dy = -(((float)pj) - 50.0f) / 86.6f;
    const float rd0 = dx * c2w[0] + dy * c2w[1] - c2w[2];
    const float rd1 = dx * c2w[4] + dy * c2w[5] - c2w[6];
    const float rd2 = dx * c2w[8] + dy * c2w[9] - c2w[10];
    const float ro0 = c2w[3], ro1 = c2w[7], ro2 = c2w[11];
    const float nrm = sqrtf(rd0 * rd0 + rd1 * rd1 + rd2 * rd2);
    const float vd0 = rd0 / nrm, vd1 = rd1 / nrm, vd2 = rd2 / nrm;

    // ---- L1 weight/bias prefetch: issue before the enc phase; L2 latency hides under trig ----
    half8 w1pf[2][4];
    float4v b1pf[4];
    if (PACKED) {
        #pragma unroll
        for (int ks = 0; ks < 2; ++ks)
            #pragma unroll
            for (int nt = 0; nt < 4; ++nt)
                w1pf[ks][nt] = wp8[(W1P_OFF >> 3) + (ks * 16 + wv * 4 + nt) * 64 + lane];
    }
    #pragma unroll
    for (int nt = 0; nt < 4; ++nt)
        b1pf[nt] = *reinterpret_cast<const float4v*>(&b1[(wv * 4 + nt) * 16 + lq * 4]);

    // ---- phase E: enc_pts (waves 0-2, inline z, hw sin/cos, permuted K layout) ----
    // col 0..2 = xyz, col 3 = pad(0), cols 4+20c+2l = {sin,cos} packed b32 per thread.
    if (tid < 192) {
        const int s = tid / 3;
        const int c = tid - 3 * s;
        const float zv = (float)z_of(s, t_rand);
        const float p = (c == 0) ? (ro0 + rd0 * zv) : ((c == 1) ? (ro1 + rd1 * zv) : (ro2 + rd2 * zv));
        _Float16* row = &encH[s * ENC_H];
        if (c == 2) {
            *reinterpret_cast<half2v*>(&row[2]) = half2v{(_Float16)p, (_Float16)0.0f};
        } else {
            row[c] = (_Float16)p;
        }
        unsigned* rowu = reinterpret_cast<unsigned*>(row);
        #pragma unroll
        for (int l = 0; l < 10; ++l) {
            const float f = p * ((float)(1 << l) * INV2PI);
            const float fr = f - floorf(f);
            const fp16x2 sc = __builtin_amdgcn_cvt_pkrtz(__builtin_amdgcn_sinf(fr),
                                                         __builtin_amdgcn_cosf(fr));
            rowu[2 + 10 * c + l] = __builtin_bit_cast(unsigned, sc);
        }
    } else if (tid < 224) {
        const int f = tid - 192;
        float v = 0.0f;
        if (f < D_DIR) {
            if (f < 3) {
                v = (f == 0) ? vd0 : ((f == 1) ? vd1 : vd2);
            } else {
                const int ff = f - 3;
                const int l = ff / 6;
                const int r = ff - 6 * l;
                const int c = r % 3;
                const float x = ((c == 0) ? vd0 : ((c == 1) ? vd1 : vd2)) * (float)(1 << l);
                v = (r < 3) ? hsin_rev(x * INV2PI) : hcos_rev(x * INV2PI);
            }
        }
        encdirH[f] = (_Float16)v;
    }
    __syncthreads();

    // ======== layer 1 (MFMA, swapped operands): C'[neuron][sample] ========
    half8 w2pf[4];   // L2 ks=0 prefetch (loaded below, before the barrier)
    {
        float4v acc[4][4];   // [nt][st]
        #pragma unroll
        for (int nt = 0; nt < 4; ++nt)
            #pragma unroll
            for (int st = 0; st < 4; ++st) acc[nt][st] = b1pf[nt];

        #pragma unroll
        for (int ks = 0; ks < 2; ++ks) {
            half8 h[4];
            #pragma unroll
            for (int st = 0; st < 4; ++st)
                h[st] = *reinterpret_cast<const half8*>(&encH[(st * 16 + lr) * ENC_H + ks * 32 + lq * 8]);
            __builtin_amdgcn_s_setprio(1);
            #pragma unroll
            for (int nt = 0; nt < 4; ++nt) {
                const half8 w = PACKED
                    ? w1pf[ks][nt]
                    : bf_w1p(w1, ks * 32 + lq * 8, (wv * 4 + nt) * 16 + lr);
                #pragma unroll
                for (int st = 0; st < 4; ++st)
                    acc[nt][st] = __builtin_amdgcn_mfma_f32_16x16x32_f16(w, h[st], acc[nt][st], 0, 0, 0);
            }
            __builtin_amdgcn_s_setprio(0);
        }
        if (PACKED) {   // prefetch L2 ks=0 weights across the barrier
            #pragma unroll
            for (int nt = 0; nt < 4; ++nt)
                w2pf[nt] = wp8[(W2P_OFF >> 3) + (wv * 4 + nt) * 64 + lane];
        }
        __syncthreads();   // ALL encH reads complete (hbuf aliases encH)
        #pragma unroll
        for (int nt = 0; nt < 4; ++nt) {
            const int nb = (wv * 4 + nt) * 16 + lq * 4;
            #pragma unroll
            for (int st = 0; st < 4; ++st)
                *reinterpret_cast<half4v*>(&hbuf[(st * 16 + lr) * H_S + nb]) = pack_relu4(acc[nt][st]);
        }
    }
    __syncthreads();

    // ======== layer 2 (MFMA): H2 = relu(H1 @ w2 + b2) ========
    half8 wdpf[2];   // dir ks=0 prefetch (loaded below, before the barrier)
    {
        float4v acc[4][4];
        #pragma unroll
        for (int nt = 0; nt < 4; ++nt) {
            const float4v bb = *reinterpret_cast<const float4v*>(&b2[(wv * 4 + nt) * 16 + lq * 4]);
            #pragma unroll
            for (int st = 0; st < 4; ++st) acc[nt][st] = bb;
        }

        // ks = 0 (prefetched weights)
        {
            half8 h[4];
            #pragma unroll
            for (int st = 0; st < 4; ++st)
                h[st] = ld_h8(&hbuf[(st * 16 + lr) * H_S + lq * 8]);
            __builtin_amdgcn_s_setprio(1);
            #pragma unroll
            for (int nt = 0; nt < 4; ++nt) {
                const half8 w = PACKED
                    ? w2pf[nt]
                    : bf_w(w2, HID, lq * 8, (wv * 4 + nt) * 16 + lr, 1 << 30);
                #pragma unroll
                for (int st = 0; st < 4; ++st)
                    acc[nt][st] = __builtin_amdgcn_mfma_f32_16x16x32_f16(w, h[st], acc[nt][st], 0, 0, 0);
            }
            __builtin_amdgcn_s_setprio(0);
        }
        // Unrolled: lets the scheduler hoist ks+1's ds_reads/weight loads into ks's MFMA shadow.
        #pragma unroll
        for (int ks = 1; ks < 8; ++ks) {
            half8 h[4];
            #pragma unroll
            for (int st = 0; st < 4; ++st)
                h[st] = ld_h8(&hbuf[(st * 16 + lr) * H_S + ks * 32 + lq * 8]);
            const half8* wk = wp8 + (W2P_OFF >> 3) + (ks * 16 + wv * 4) * 64 + lane;
            __builtin_amdgcn_s_setprio(1);
            #pragma unroll
            for (int nt = 0; nt < 4; ++nt) {
                const half8 w = PACKED
                    ? wk[nt * 64]
                    : bf_w(w2, HID, ks * 32 + lq * 8, (wv * 4 + nt) * 16 + lr, 1 << 30);
                #pragma unroll
                for (int st = 0; st < 4; ++st)
                    acc[nt][st] = __builtin_amdgcn_mfma_f32_16x16x32_f16(w, h[st], acc[nt][st], 0, 0, 0);
            }
            __builtin_amdgcn_s_setprio(0);
        }
        if (PACKED) {   // prefetch dir ks=0 weights across the barrier
            #pragma unroll
            for (int nt = 0; nt < 2; ++nt)
                wdpf[nt] = wp8[(WDP_OFF >> 3) + (wv * 2 + nt) * 64 + lane];
        }
        __syncthreads();   // all H1 reads complete before in-place overwrite
        #pragma unroll
        for (int nt = 0; nt < 4; ++nt) {
            const int nb = (wv * 4 + nt) * 16 + lq * 4;
            #pragma unroll
            for (int st = 0; st < 4; ++st)
                *reinterpret_cast<half4v*>(&hbuf[(st * 16 + lr) * H_S + nb]) = pack_relu4(acc[nt][st]);
        }
    }
    __syncthreads();

    // ======== dir layer + sigma (MFMA, K=256 + 27-dim enc_dir tail as 9th ks) ========
    // Sigma balanced: wave w accumulates sigma over ks in {2w, 2w+1}; partials summed later.
    float4v accd[2][4];
    float4v accs[4];
    {
        #pragma unroll
        for (int nt = 0; nt < 2; ++nt) {
            const float4v bb = *reinterpret_cast<const float4v*>(&b_dir[(wv * 2 + nt) * 16 + lq * 4]);
            #pragma unroll
            for (int st = 0; st < 4; ++st) accd[nt][st] = bb;
        }
        #pragma unroll
        for (int st = 0; st < 4; ++st) accs[st] = float4v{0.f, 0.f, 0.f, 0.f};

        // ks = 0 (prefetched dir weights; sigma ks0 belongs to wave 0)
        {
            half8 h[4];
            #pragma unroll
            for (int st = 0; st < 4; ++st)
                h[st] = ld_h8(&hbuf[(st * 16 + lr) * H_S + lq * 8]);
            __builtin_amdgcn_s_setprio(1);
            #pragma unroll
            for (int nt = 0; nt < 2; ++nt) {
                const half8 w = PACKED
                    ? wdpf[nt]
                    : bf_w(w_dir, HID_DIR, lq * 8, (wv * 2 + nt) * 16 + lr, 1 << 30);
                #pragma unroll
                for (int st = 0; st < 4; ++st)
                    accd[nt][st] = __builtin_amdgcn_mfma_f32_16x16x32_f16(w, h[st], accd[nt][st], 0, 0, 0);
            }
            if (wv == 0) {
                const half8 w = PACKED
                    ? wp8[(WDP_OFF >> 3) + 8 * 64 + lane]
                    : bf_sig(w_sig, lq * 8, lr);
                #pragma unroll
                for (int st = 0; st < 4; ++st)
                    accs[st] = __builtin_amdgcn_mfma_f32_16x16x32_f16(w, h[st], accs[st], 0, 0, 0);
            }
            __builtin_amdgcn_s_setprio(0);
        }
        #pragma unroll
        for (int ks = 1; ks < 8; ++ks) {
            half8 h[4];
            #pragma unroll
            for (int st = 0; st < 4; ++st)
                h[st] = ld_h8(&hbuf[(st * 16 + lr) * H_S + ks * 32 + lq * 8]);
            const half8* wk = wp8 + (WDP_OFF >> 3) + (ks * 9 + wv * 2) * 64 + lane;
            __builtin_amdgcn_s_setprio(1);
            #pragma unroll
            for (int nt = 0; nt < 2; ++nt) {
                const half8 w = PACKED
                    ? wk[nt * 64]
                    : bf_w(w_dir, HID_DIR, ks * 32 + lq * 8, (wv * 2 + nt) * 16 + lr, 1 << 30);
                #pragma unroll
                for (int st = 0; st < 4; ++st)
                    accd[nt][st] = __builtin_amdgcn_mfma_f32_16x16x32_f16(w, h[st], accd[nt][st], 0, 0, 0);
            }
            if ((ks >> 1) == wv) {   // this wave's sigma K-slice
                const half8 w = PACKED
                    ? wp8[(WDP_OFF >> 3) + (ks * 9 + 8) * 64 + lane]
                    : bf_sig(w_sig, ks * 32 + lq * 8, lr);
                #pragma unroll
                for (int st = 0; st < 4; ++st)
                    accs[st] = __builtin_amdgcn_mfma_f32_16x16x32_f16(w, h[st], accs[st], 0, 0, 0);
            }
            __builtin_amdgcn_s_setprio(0);
        }
        // tail ks=8: B = enc_dir broadcast (ray-uniform)
        {
            const half8 he = *reinterpret_cast<const half8*>(&encdirH[lq * 8]);
            const half8* wk = wp8 + (WDP_OFF >> 3) + (8 * 9 + wv * 2) * 64 + lane;
            __builtin_amdgcn_s_setprio(1);
            #pragma unroll
            for (int nt = 0; nt < 2; ++nt) {
                const half8 w = PACKED
                    ? wk[nt * 64]
                    : bf_w(w_dir, HID_DIR, HID + lq * 8, (wv * 2 + nt) * 16 + lr, HID + D_DIR);
                #pragma unroll
                for (int st = 0; st < 4; ++st)
                    accd[nt][st] = __builtin_amdgcn_mfma_f32_16x16x32_f16(w, he, accd[nt][st], 0, 0, 0);
            }
            __builtin_amdgcn_s_setprio(0);
        }
    }
    __syncthreads();   // all H2 reads complete

    // HD -> hbuf (HD_S layout); sigma partials -> sigp
    #pragma unroll
    for (int nt = 0; nt < 2; ++nt) {
        const int nb = (wv * 2 + nt) * 16 + lq * 4;
        #pragma unroll
        for (int st = 0; st < 4; ++st)
            *reinterpret_cast<half4v*>(&hbuf[(st * 16 + lr) * HD_S + nb]) = pack_relu4(accd[nt][st]);
    }
    if (lq == 0) {
        #pragma unroll
        for (int st = 0; st < 4; ++st)
            sigp[wv][st * 16 + lr] = accs[st][0];
    }
    __syncthreads();

    // ======== rgb head (MFMA): wave wv handles sample-tile wv ========
    // Wave 0 concurrently reduces the sigma partials (ready before the next barrier).
    if (tid < NS)
        sigb[tid] = ((sigp[0][tid] + sigp[1][tid]) + (sigp[2][tid] + sigp[3][tid])) + b_sig[0];
    {
        float4v accr = float4v{0.f, 0.f, 0.f, 0.f};
        const half8* wk = wp8 + (WRGB_OFF >> 3) + lane;
        __builtin_amdgcn_s_setprio(1);
        #pragma unroll
        for (int ks = 0; ks < 4; ++ks) {
            const half8 h = ld_h8(&hbuf[(wv * 16 + lr) * HD_S + ks * 32 + lq * 8]);
            const half8 w = PACKED
                ? wk[ks * 64]
                : bf_rgb(w_rgb, ks * 32 + lq * 8, lr);
            accr = __builtin_amdgcn_mfma_f32_16x16x32_f16(w, h, accr, 0, 0, 0);
        }
        __builtin_amdgcn_s_setprio(0);
        if (lq == 0) {
            #pragma unroll
            for (int r = 0; r < 3; ++r) {
                const float a = accr[r] + b_rgb[r];
                rgbb[(wv * 16 + lr) * 3 + r] = 1.0f / (1.0f + expf(-a));
            }
        }
    }
    __syncthreads();   // rgb reads + sigb reduction done -> scr reusable by razor

    // ======== conditional f64 razor for sigma[63] (aliases scr) ========
    // Threshold 0.01: main-path sigma error ~3e-4 (<=1e-3 pessimistic) -> 10x margin.
    if (fabsf(sigb[63]) < 0.01f) {
        {
            const double z63 = z_of(63, t_rand);
            const double p0 = (double)ro0 + (double)rd0 * z63;
            const double p1 = (double)ro1 + (double)rd1 * z63;
            const double p2 = (double)ro2 + (double)rd2 * z63;
            if (tid < D_PTS) {
                const int f = tid;
                double v;
                if (f < 3) {
                    v = (f == 0) ? p0 : ((f == 1) ? p1 : p2);
                } else {
                    const int ff = f - 3;
                    const int l = ff / 6;
                    const int r = ff - 6 * l;
                    const int c = r % 3;
                    const double x = ((c == 0) ? p0 : ((c == 1) ? p1 : p2)) * (double)(1 << l);
                    v = (r < 3) ? sin(x) : cos(x);
                }
                encD[f] = v;
            }
        }
        __syncthreads();
        {
            double a0 = 0.0, a1 = 0.0, a2 = 0.0, a3 = 0.0;
            int k = 0;
            for (; k + 4 <= 60; k += 4) {
                a0 += encD[k]     * (double)w1[(k)     * HID + tid];
                a1 += encD[k + 1] * (double)w1[(k + 1) * HID + tid];
                a2 += encD[k + 2] * (double)w1[(k + 2) * HID + tid];
                a3 += encD[k + 3] * (double)w1[(k + 3) * HID + tid];
            }
            a0 += encD[60] * (double)w1[60 * HID + tid];
            a1 += encD[61] * (double)w1[61 * HID + tid];
            a2 += encD[62] * (double)w1[62 * HID + tid];
            const double acc = ((a0 + a1) + (a2 + a3)) + (double)b1[tid];
            h1d[tid] = fmax(acc, 0.0);
        }
        __syncthreads();
        {
            double a0 = 0.0, a1 = 0.0, a2 = 0.0, a3 = 0.0;
            for (int k = 0; k < HID; k += 4) {
                a0 += h1d[k]     * (double)w2[(k)     * HID + tid];
                a1 += h1d[k + 1] * (double)w2[(k + 1) * HID + tid];
                a2 += h1d[k + 2] * (double)w2[(k + 2) * HID + tid];
                a3 += h1d[k + 3] * (double)w2[(k + 3) * HID + tid];
            }
            const double acc = ((a0 + a1) + (a2 + a3)) + (double)b2[tid];
            h2d[tid] = fmax(acc, 0.0);
        }
        __syncthreads();
        if (tid < 64) {
            double p = 0.0;
            #pragma unroll
            for (int m = 0; m < 4; ++m)
                p += h2d[tid * 4 + m] * (double)w_sig[tid * 4 + m];
            #pragma unroll
            for (int off = 1; off < 64; off <<= 1)
                p += __shfl_xor(p, off, 64);
            if (tid == 0) sigb[63] = (float)(p + (double)b_sig[0]);
        }
    }
    __syncthreads();

    // ======== volume compositing (wave 0, inline z) ========
    if (tid < NS) {
        const int s = tid;
        const float sgv = sigb[s];
        const float zv  = (float)z_of(s, t_rand);
        const float zn  = __shfl_down(zv, 1, 64);
        const float dist = (s < 63) ? (zn - zv) : 1.0e10f;
        const float alpha = 1.0f - expf(-fmaxf(sgv, 0.0f) * dist * nrm);
        float P = 1.0f - alpha;
        #pragma unroll
        for (int off = 1; off < 64; off <<= 1) {
            const float p = __shfl_up(P, off, 64);
            if (s >= off) P *= p;
        }
        float T = __shfl_up(P, 1, 64);
        if (s == 0) T = 1.0f;
        const float wgt = alpha * T;
        float r0 = wgt * rgbb[s * 3 + 0];
        float r1 = wgt * rgbb[s * 3 + 1];
        float r2 = wgt * rgbb[s * 3 + 2];
        #pragma unroll
        for (int off = 32; off > 0; off >>= 1) {
            r0 += __shfl_xor(r0, off, 64);
            r1 += __shfl_xor(r1, off, 64);
            r2 += __shfl_xor(r2, off, 64);
        }
        if (s == 0) {
            out[ray * 3 + 0] = r0;
            out[ray * 3 + 1] = r1;
            out[ray * 3 + 2] = r2;
        }
    }
}

} // namespace

extern "C" void kernel_launch(void* const* d_in, const int* in_sizes, int n_in,
                              void* d_out, int out_size, void* d_ws, size_t ws_size,
                              hipStream_t stream) {
    const float* c2w    = (const float*)d_in[0];
    const float* t_rand = (const float*)d_in[1];
    const float* w1     = (const float*)d_in[2];
    const float* b1     = (const float*)d_in[3];
    const float* w2     = (const float*)d_in[4];
    const float* b2     = (const float*)d_in[5];
    const float* w_sig  = (const float*)d_in[6];
    const float* b_sig  = (const float*)d_in[7];
    const float* w_dir  = (const float*)d_in[8];
    const float* b_dir  = (const float*)d_in[9];
    const float* w_rgb  = (const float*)d_in[10];
    const float* b_rgb  = (const float*)d_in[11];

    (void)in_sizes; (void)n_in; (void)out_size;

    const bool packed = (ws_size >= (size_t)(WPACK_HALFS * 2));
    if (packed) {
        _Float16* wp = (_Float16*)d_ws;
        hipLaunchKernelGGL(prepack, dim3((WPACK_HALFS + NTH - 1) / NTH), dim3(NTH), 0, stream,
                           w1, w2, w_dir, w_sig, w_rgb, wp);
        hipLaunchKernelGGL((nerf_fused<true>), dim3(100 * 100), dim3(NTH), 0, stream,
                           c2w, t_rand, w1, b1, w2, b2, w_sig, b_sig,
                           w_dir, b_dir, w_rgb, b_rgb, (const _Float16*)wp, (float*)d_out);
    } else {
        hipLaunchKernelGGL((nerf_fused<false>), dim3(100 * 100), dim3(NTH), 0, stream,
                           c2w, t_rand, w1, b1, w2, b2, w_sig, b_sig,
                           w_dir, b_dir, w_rgb, b_rgb, (const _Float16*)nullptr, (float*)d_out);
    }
}